// Round 4
// baseline (403.734 us; speedup 1.0000x reference)
//
#include <hip/hip_runtime.h>

#define EPS_F 1e-5f

// DPP move with explicit 'old' (identity) for masked/invalid lanes.
#define DPPF(old, x, ctrl, rm, bm) \
  __int_as_float(__builtin_amdgcn_update_dpp(__float_as_int(old), __float_as_int(x), ctrl, rm, bm, false))

// Canonical gfx9 wave64 inclusive scans: row_shr 1,2,4,8 + row_bcast15/31.
__device__ __forceinline__ float scan_add64(float x) {
  x += DPPF(0.0f, x, 0x111, 0xf, 0xf);
  x += DPPF(0.0f, x, 0x112, 0xf, 0xf);
  x += DPPF(0.0f, x, 0x114, 0xf, 0xf);
  x += DPPF(0.0f, x, 0x118, 0xf, 0xf);
  x += DPPF(0.0f, x, 0x142, 0xa, 0xf);
  x += DPPF(0.0f, x, 0x143, 0xc, 0xf);
  return x;
}
__device__ __forceinline__ float scan_mul64(float x) {
  x *= DPPF(1.0f, x, 0x111, 0xf, 0xf);
  x *= DPPF(1.0f, x, 0x112, 0xf, 0xf);
  x *= DPPF(1.0f, x, 0x114, 0xf, 0xf);
  x *= DPPF(1.0f, x, 0x118, 0xf, 0xf);
  x *= DPPF(1.0f, x, 0x142, 0xa, 0xf);
  x *= DPPF(1.0f, x, 0x143, 0xc, 0xf);
  return x;
}
__device__ __forceinline__ float wave_total(float x) {
  float s = scan_add64(x);
  return __int_as_float(__builtin_amdgcn_readlane(__float_as_int(s), 63));
}

__global__ __launch_bounds__(256) void nerf_volrend(
    const float* __restrict__ rays,
    const float* __restrict__ sigc,
    const float* __restrict__ rgbc,
    const float* __restrict__ sigf,
    const float* __restrict__ rgbf,
    float* __restrict__ out, int n_rays)
{
  const int wave = threadIdx.x >> 6;
  const int lane = threadIdx.x & 63;
  const int ray  = (blockIdx.x << 2) + wave;

  // Wave-private LDS slices: no __syncthreads needed (same-wave DS ops in order).
  __shared__ float s_cdf[4][64];   // 63 used
  __shared__ int   s_cc [4][64];   // fine-sample coarse-ranks (sorted)
  __shared__ float s_zcb[4][128];  // merged z

  // ------- prefetch ALL global loads (addresses depend only on ray) -------
  const float2 nf   = *(const float2*)(rays + (size_t)ray*8 + 6);   // near, far
  const float  sgcv = sigc[(size_t)ray*64 + lane];
  const float  r0   = rgbc[(size_t)ray*192 + lane*3 + 0];
  const float  r1   = rgbc[(size_t)ray*192 + lane*3 + 1];
  const float  r2   = rgbc[(size_t)ray*192 + lane*3 + 2];
  const float2 sgf2 = ((const float2*)(sigf + (size_t)ray*128))[lane];
  const float* rb   = rgbf + (size_t)ray*384 + lane*6;
  const float2 rA   = *(const float2*)(rb + 0);
  const float2 rB   = *(const float2*)(rb + 2);
  const float2 rC   = *(const float2*)(rb + 4);
  __builtin_amdgcn_sched_barrier(0);   // pin loads at top; waits remain at first use

  const float nearv = nf.x, farv = nf.y;

  // ---------------- coarse composite ----------------
  const float t  = (float)lane * 0.015625f;
  const float tn = (float)(lane + 1) * 0.015625f;
  const float z     = nearv * (1.0f - t)  + farv * t;
  const float znext = nearv * (1.0f - tn) + farv * tn;   // == ref z[lane+1]
  const float delta = (lane == 63) ? 1e10f : (znext - z);
  const float sgv = fmaxf(sgcv, 0.0f);
  const float a  = 1.0f - __expf(-delta * sgv);
  const float sh = 1.0f - a + 1e-10f;

  const float pin = scan_mul64(sh);          // inclusive prefix product
  float T = __shfl_up(pin, 1);
  if (lane == 0) T = 1.0f;
  const float w = a * T;

  const float wsum = wave_total(w);
  const float cR = wave_total(w * r0);
  const float cG = wave_total(w * r1);
  const float cB = wave_total(w * r2);
  const float cD = wave_total(w * z);

  if (lane == 0) {
    out[ray*3 + 0]      = cR + 1.0f - wsum;
    out[ray*3 + 1]      = cG + 1.0f - wsum;
    out[ray*3 + 2]      = cB + 1.0f - wsum;
    out[n_rays*3 + ray] = wsum;
    out[n_rays*4 + ray] = cD + (1.0f - wsum) * farv;
  }

  // ---------------- sample_fine (inverse-CDF) ----------------
  const float wnext = __shfl_down(w, 1);               // weights[lane+1]
  const float wp    = (lane < 62) ? (wnext + EPS_F) : 0.0f;
  const float wpsum = wave_total(wp);
  const float csum  = scan_add64(wp / wpsum);          // inclusive cdf

  if (lane < 62) s_cdf[wave][lane + 1] = csum;
  if (lane == 0) s_cdf[wave][0] = 0.0f;

  const float* cdf = s_cdf[wave];
  const float u = (lane == 63) ? 1.0f : (float)lane * (1.0f / 63.0f);
  // searchsorted(cdf[0..62], u, side='right') == count(cdf <= u)
  int pos = 0;
  #pragma unroll
  for (int stp = 32; stp; stp >>= 1) {
    int np = pos + stp;
    if (np <= 63 && cdf[np - 1] <= u) pos = np;
  }
  const int below = max(pos - 1, 0);
  const int above = min(pos, 62);
  const float cdf_b = cdf[below], cdf_a = cdf[above];
  // bins arithmetic (uniform z grid): bin(k) = 0.5*(z(k)+z(k+1))
  const float tb  = (float)below * 0.015625f, tb1 = (float)(below + 1) * 0.015625f;
  const float ta  = (float)above * 0.015625f, ta1 = (float)(above + 1) * 0.015625f;
  const float bin_b = 0.5f * ((nearv*(1.0f-tb)  + farv*tb)  + (nearv*(1.0f-tb1) + farv*tb1));
  const float bin_a = 0.5f * ((nearv*(1.0f-ta)  + farv*ta)  + (nearv*(1.0f-ta1) + farv*ta1));
  float dn = cdf_a - cdf_b;
  if (dn < EPS_F) dn = 1.0f;
  const float zf = bin_b + (u - cdf_b) / dn * (bin_a - bin_b);

  // ---------------- merge via ranks (uniform coarse grid) ----------------
  const float inv_step = 64.0f / (farv - nearv);
  int cc = (int)floorf((zf - nearv) * inv_step) + 1;
  cc = min(max(cc, 0), 64);
  s_cc[wave][lane] = cc;                       // sorted (zf sorted)
  s_zcb[wave][lane + cc] = zf;                 // fine scatter

  // cf_i = #{j: cc_j <= i}  (rank of coarse sample i among fine samples)
  const int* ccl = s_cc[wave];
  int cf = 0;
  #pragma unroll
  for (int stp = 64; stp; stp >>= 1) {
    int np = cf + stp;
    if (np <= 64 && ccl[np - 1] <= lane) cf = np;
  }
  s_zcb[wave][lane + cf] = z;                  // coarse scatter

  // ---------------- fine composite (2 samples / lane) ----------------
  const float* zcb = s_zcb[wave];
  const float2 zp = ((const float2*)zcb)[lane];        // ds_read_b64
  const float z0 = zp.x, z1 = zp.y;
  const float z2 = zcb[(lane == 63) ? 127 : (2*lane + 2)];
  const float d0 = z1 - z0;
  const float d1 = (lane == 63) ? 1e10f : (z2 - z1);

  const float s0 = fmaxf(sgf2.x, 0.0f);
  const float s1 = fmaxf(sgf2.y, 0.0f);
  const float a0 = 1.0f - __expf(-d0 * s0);
  const float a1 = 1.0f - __expf(-d1 * s1);
  const float t0 = 1.0f - a0 + 1e-10f;
  const float t1 = 1.0f - a1 + 1e-10f;

  const float pp = scan_mul64(t0 * t1);        // pair-product scan
  float Pex = __shfl_up(pp, 1);
  if (lane == 0) Pex = 1.0f;
  const float w0 = a0 * Pex;
  const float w1 = a1 * Pex * t0;

  const float fR = wave_total(w0 * rA.x + w1 * rB.y);
  const float fG = wave_total(w0 * rA.y + w1 * rC.x);
  const float fB = wave_total(w0 * rB.x + w1 * rC.y);
  const float fD = wave_total(w0 * z0   + w1 * z1);
  const float fW = wave_total(w0 + w1);

  if (lane == 0) {
    out[n_rays*5 + ray*3 + 0] = fR + 1.0f - fW;
    out[n_rays*5 + ray*3 + 1] = fG + 1.0f - fW;
    out[n_rays*5 + ray*3 + 2] = fB + 1.0f - fW;
    out[n_rays*8 + ray]       = fW;
    out[n_rays*9 + ray]       = fD + (1.0f - fW) * farv;
  }
}

extern "C" void kernel_launch(void* const* d_in, const int* in_sizes, int n_in,
                              void* d_out, int out_size, void* d_ws, size_t ws_size,
                              hipStream_t stream) {
  const float* rays = (const float*)d_in[0];
  const float* sigc = (const float*)d_in[1];
  const float* rgbc = (const float*)d_in[2];
  const float* sigf = (const float*)d_in[3];
  const float* rgbf = (const float*)d_in[4];
  float* out = (float*)d_out;
  const int n_rays = in_sizes[0] / 8;       // 131072
  const int blocks = n_rays / 4;            // 4 rays (waves) per 256-thread block
  nerf_volrend<<<blocks, 256, 0, stream>>>(rays, sigc, rgbc, sigf, rgbf, out, n_rays);
}